// Round 10
// baseline (389.055 us; speedup 1.0000x reference)
//
#include <hip/hip_runtime.h>

#define NODE_D 128
#define NUM_GRAPHS 64
#define SCHUNK 2048   // elements per scan block (256 thr x 8)

typedef __bf16 v8bf __attribute__((ext_vector_type(8)));
typedef __bf16 v4bf __attribute__((ext_vector_type(4)));
typedef float  v4f  __attribute__((ext_vector_type(4)));

// ---------------------------------------------------------------------------
// CSR build, step 1: degree histogram (int atomics — cheap)
// ---------------------------------------------------------------------------
__global__ __launch_bounds__(256) void k_hist(
    const int* __restrict__ dst, int* deg, int E)
{
    int e = blockIdx.x * 256 + threadIdx.x;
    if (e < E) atomicAdd(&deg[dst[e]], 1);
}

// ---------------------------------------------------------------------------
// CSR build, step 2a: per-block partial sums of deg
// ---------------------------------------------------------------------------
__global__ __launch_bounds__(256) void k_scan_partial(
    const int* __restrict__ deg, int* partial, int N)
{
    __shared__ int sbuf[256];
    int base = blockIdx.x * SCHUNK;
    int t = threadIdx.x;
    int s = 0;
#pragma unroll
    for (int i = 0; i < 8; ++i) {
        int idx = base + i * 256 + t;
        if (idx < N) s += deg[idx];
    }
    sbuf[t] = s;
    __syncthreads();
    for (int off = 128; off > 0; off >>= 1) {
        if (t < off) sbuf[t] += sbuf[t + off];
        __syncthreads();
    }
    if (t == 0) partial[blockIdx.x] = sbuf[0];
}

// ---------------------------------------------------------------------------
// CSR build, step 2b: serial exclusive scan of block partials (nb ~ 49)
// ---------------------------------------------------------------------------
__global__ void k_scan_top(int* partial, int nb)
{
    if (threadIdx.x == 0 && blockIdx.x == 0) {
        int run = 0;
        for (int i = 0; i < nb; ++i) { int v = partial[i]; partial[i] = run; run += v; }
    }
}

// ---------------------------------------------------------------------------
// CSR build, step 2c: per-block exclusive scan -> offs, cursor
// ---------------------------------------------------------------------------
__global__ __launch_bounds__(256) void k_scan_final(
    const int* __restrict__ deg, const int* __restrict__ partial,
    int* offs, int* cursor, int N)
{
    __shared__ int sbuf[256];
    int base = blockIdx.x * SCHUNK;
    int t = threadIdx.x;
    int idx0 = base + t * 8;
    int loc[8];
    int s = 0;
#pragma unroll
    for (int i = 0; i < 8; ++i) {
        int idx = idx0 + i;
        int v = (idx < N) ? deg[idx] : 0;
        loc[i] = s;
        s += v;
    }
    sbuf[t] = s;
    __syncthreads();
    for (int off = 1; off < 256; off <<= 1) {
        int tmp = (t >= off) ? sbuf[t - off] : 0;
        __syncthreads();
        sbuf[t] += tmp;
        __syncthreads();
    }
    int pre = sbuf[t] - s + partial[blockIdx.x];
#pragma unroll
    for (int i = 0; i < 8; ++i) {
        int idx = idx0 + i;
        if (idx < N) {
            int v = pre + loc[i];
            offs[idx]   = v;
            cursor[idx] = v;
        }
    }
}

// ---------------------------------------------------------------------------
// CSR build, step 3: bucket src ids into CSR order
// ---------------------------------------------------------------------------
__global__ __launch_bounds__(256) void k_fill(
    const int* __restrict__ src, const int* __restrict__ dst,
    int* cursor, int* srcs, int E)
{
    int e = blockIdx.x * 256 + threadIdx.x;
    if (e < E) {
        int pos = atomicAdd(&cursor[dst[e]], 1);
        srcs[pos] = src[e];
    }
}

// ---------------------------------------------------------------------------
// Graph bounds: gs[g] = first row of graph g (batch is sorted); gs[64] = N.
// Handles empty graphs (gs[g] = start of next non-empty graph).
// ---------------------------------------------------------------------------
__global__ __launch_bounds__(256) void k_bounds(
    const int* __restrict__ batch, int* __restrict__ gs, int N)
{
    int r = blockIdx.x * 256 + threadIdx.x;
    if (r >= N) return;
    if (r == 0) {
        for (int g = 0; g <= batch[0]; ++g) gs[g] = 0;
    } else {
        int b0 = batch[r - 1], b1 = batch[r];
        for (int g = b0 + 1; g <= b1; ++g) gs[g] = r;
    }
    if (r == N - 1) {
        for (int g = batch[N - 1] + 1; g <= NUM_GRAPHS; ++g) gs[g] = N;
    }
}

// ---------------------------------------------------------------------------
// Weight prep (both layers in one launch):
// Wt[c][k] = bf16( k<128 ? Wl[k][c] : Wr[k-128][c] )
// ---------------------------------------------------------------------------
__global__ __launch_bounds__(256) void k_prep2(
    const float* __restrict__ W1l, const float* __restrict__ W1r,
    const float* __restrict__ W2l, const float* __restrict__ W2r,
    unsigned short* __restrict__ Wt1, unsigned short* __restrict__ Wt2)
{
    int idx = blockIdx.x * 256 + threadIdx.x;   // 0..65535
    int which = idx >> 15;
    int i = idx & 32767;
    int k = i & 255;
    int c = i >> 8;
    const float* Wl = which ? W2l : W1l;
    const float* Wr = which ? W2r : W1r;
    unsigned short* Wt = which ? Wt2 : Wt1;
    float v = (k < 128) ? Wl[k * 128 + c] : Wr[(k - 128) * 128 + c];
    __bf16 b = (__bf16)v;
    Wt[c * 256 + k] = __builtin_bit_cast(unsigned short, b);
}

// ---------------------------------------------------------------------------
// Feature prep: xb = bf16(x), vectorized 8 elems/thread
// ---------------------------------------------------------------------------
__global__ __launch_bounds__(256) void k_prep_x(
    const float* __restrict__ x, unsigned short* __restrict__ xb, long n8)
{
    long idx = (long)blockIdx.x * 256 + threadIdx.x;   // over n8 = N*128/8
    if (idx >= n8) return;
    const float* p = x + idx * 8;
    float4 v0 = *(const float4*)p;
    float4 v1 = *(const float4*)(p + 4);
    v8bf b;
    b[0] = (__bf16)v0.x; b[1] = (__bf16)v0.y; b[2] = (__bf16)v0.z; b[3] = (__bf16)v0.w;
    b[4] = (__bf16)v1.x; b[5] = (__bf16)v1.y; b[6] = (__bf16)v1.z; b[7] = (__bf16)v1.w;
    *(v8bf*)(xb + idx * 8) = b;
}

// ---------------------------------------------------------------------------
// Pull-aggregate + mean (bf16 in / bf16 out, fp32 accum).
// Half-wave (32 lanes) per node, 8 nodes / 256-thread block.
// Neighbor ids prefetched lane-parallel then broadcast via __shfl.
// ---------------------------------------------------------------------------
__global__ __launch_bounds__(256) void k_gather_bf(
    const unsigned short* __restrict__ Xb, const int* __restrict__ srcs,
    const int* __restrict__ offs, const int* __restrict__ deg,
    unsigned short* __restrict__ outb, int N)
{
    int node = blockIdx.x * 8 + (threadIdx.x >> 5);
    if (node >= N) return;
    int lane  = threadIdx.x & 31;
    int start = offs[node];
    int d     = deg[node];
    float a0 = 0.f, a1 = 0.f, a2 = 0.f, a3 = 0.f;
    for (int base = 0; base < d; base += 32) {
        int cnt = min(d - base, 32);
        int sid = (lane < cnt) ? srcs[start + base + lane] : 0;
        for (int j = 0; j < cnt; ++j) {
            int s = __shfl(sid, j, 32);
            v4bf v = *(const v4bf*)(Xb + (size_t)s * NODE_D + lane * 4);
            a0 += (float)v[0]; a1 += (float)v[1];
            a2 += (float)v[2]; a3 += (float)v[3];
        }
    }
    float r = 1.0f / fmaxf((float)d, 1.0f);
    v4bf o;
    o[0] = (__bf16)(a0 * r); o[1] = (__bf16)(a1 * r);
    o[2] = (__bf16)(a2 * r); o[3] = (__bf16)(a3 * r);
    *(v4bf*)(outb + (size_t)node * NODE_D + lane * 4) = o;
}

// ---------------------------------------------------------------------------
// MFMA SAGE GEMM: y = maybe_relu([A0 || A1] @ W + bias).
// A0, A1 are bf16 [N][128]; Wt bf16 [128 cols][256 k] transposed.
// Block: 128 rows x 128 cols, 4 waves.
// mode 0: store y fp32; mode 1: store y bf16;
// mode 2: POOL — no y store; segment-reduce rows by batch[] into LDS
//         pgsum (sorted batch => block spans <=2-3 graphs; slot fallback
//         to global atomics), flush <=384 atomics/block into gsum_g.
//         mean(z+b) = (sum z + cnt*b)/cnt, so bias-in-epilogue stays exact;
//         empty graphs never receive adds -> stay 0 (matches reference).
// ---------------------------------------------------------------------------
#define GROWS 128
#define GKC   64
#define GSTR  (GKC + 8)   // 72 bf16 rows -> <=2-way bank aliasing (free, m136)
#define PSLOTS 3

__global__ __launch_bounds__(256) void k_gemm_mfma(
    const unsigned short* __restrict__ A0,    // [N][128] bf16 aggregate
    const unsigned short* __restrict__ A1,    // [N][128] bf16 x or h
    const unsigned short* __restrict__ Wt,    // [128][256] bf16 bits
    const float* __restrict__ bias,           // [128] fp32
    void* __restrict__ outp,                  // y out (modes 0/1), unused mode 2
    const int* __restrict__ batch,            // [N] sorted graph ids (mode 2)
    float* __restrict__ gsum_g,               // [64][128] pool accum (mode 2)
    int N, int do_relu, int mode)
{
    __shared__ __bf16 sA[GROWS][GSTR];
    __shared__ __bf16 sW[GROWS][GSTR];
    __shared__ float pgsum[PSLOTS][NODE_D];

    const int t    = threadIdx.x;
    const int wave = t >> 6;          // 0..3
    const int lane = t & 63;
    const int l15  = lane & 15;
    const int lg   = lane >> 4;       // 0..3
    const int row0 = blockIdx.x * GROWS;

    if (mode == 2 && t < NODE_D) {
#pragma unroll
        for (int s = 0; s < PSLOTS; ++s) pgsum[s][t] = 0.f;
    }

    v4f acc[2][8];
#pragma unroll
    for (int m = 0; m < 2; ++m)
#pragma unroll
        for (int n = 0; n < 8; ++n)
            acc[m][n] = (v4f){0.f, 0.f, 0.f, 0.f};

    float bk[8];
#pragma unroll
    for (int n = 0; n < 8; ++n) bk[n] = bias[n * 16 + l15];

    for (int kc = 0; kc < 4; ++kc) {
        const int kbase = kc * GKC;                       // 0,64,128,192
        const unsigned short* Asrc = (kbase < NODE_D) ? A0 : A1;
        const int koff = kbase & (NODE_D - 1);            // 0 or 64
        // ---- stage A chunk: 128 rows x 64 k bf16. 4 x 16B per thread.
#pragma unroll
        for (int i = 0; i < 4; ++i) {
            int fi = i * 256 + t;     // 0..1023
            int r  = fi >> 3;         // 0..127
            int k8 = fi & 7;          // 0..7
            int row = row0 + r;
            v8bf v = (v8bf)(__bf16)0.f;
            if (row < N) v = *(const v8bf*)(Asrc + (size_t)row * NODE_D + koff + k8 * 8);
            *(v8bf*)&sA[r][k8 * 8] = v;
        }
        // ---- stage W chunk: 128 cols x 64 k bf16. 4 x 16B per thread.
#pragma unroll
        for (int i = 0; i < 4; ++i) {
            int fi = i * 256 + t;     // 0..1023
            int c  = fi >> 3;         // 0..127
            int k8 = fi & 7;          // 0..7
            v8bf w = *(const v8bf*)((const __bf16*)Wt + c * 256 + kbase + k8 * 8);
            *(v8bf*)&sW[c][k8 * 8] = w;
        }
        __syncthreads();
        // ---- compute: 2 k-steps of 32
#pragma unroll
        for (int ks = 0; ks < 2; ++ks) {
            const int kk = ks * 32 + lg * 8;
            v8bf a0 = *(const v8bf*)&sA[wave * 32 +  0 + l15][kk];
            v8bf a1 = *(const v8bf*)&sA[wave * 32 + 16 + l15][kk];
#pragma unroll
            for (int n = 0; n < 8; ++n) {
                v8bf b = *(const v8bf*)&sW[n * 16 + l15][kk];
                acc[0][n] = __builtin_amdgcn_mfma_f32_16x16x32_bf16(a0, b, acc[0][n], 0, 0, 0);
                acc[1][n] = __builtin_amdgcn_mfma_f32_16x16x32_bf16(a1, b, acc[1][n], 0, 0, 0);
            }
        }
        __syncthreads();
    }
    // ---- epilogue
    if (mode == 2) {
        // pooled: segment-reduce this block's rows into pgsum by graph id
        const int gfirst = batch[row0 < N ? row0 : (N - 1)];
#pragma unroll
        for (int m = 0; m < 2; ++m) {
#pragma unroll
            for (int rr = 0; rr < 4; ++rr) {
                int row = row0 + wave * 32 + m * 16 + lg * 4 + rr;
                if (row < N) {
                    int rel = batch[row] - gfirst;
#pragma unroll
                    for (int n = 0; n < 8; ++n) {
                        float v = acc[m][n][rr] + bk[n];
                        if (rel < PSLOTS) atomicAdd(&pgsum[rel][n * 16 + l15], v);
                        else atomicAdd(&gsum_g[(gfirst + rel) * NODE_D + n * 16 + l15], v);
                    }
                }
            }
        }
        __syncthreads();
        if (t < PSLOTS * NODE_D) {
            int rel = t >> 7;          // 0..2
            int col = t & 127;
            float v = pgsum[rel][col];
            int g = gfirst + rel;
            if (v != 0.f && g < NUM_GRAPHS)
                atomicAdd(&gsum_g[g * NODE_D + col], v);
        }
    } else {
        float* outf = (float*)outp;
        unsigned short* outh = (unsigned short*)outp;
#pragma unroll
        for (int m = 0; m < 2; ++m) {
#pragma unroll
            for (int rr = 0; rr < 4; ++rr) {
                int row = row0 + wave * 32 + m * 16 + lg * 4 + rr;
                if (row < N) {
#pragma unroll
                    for (int n = 0; n < 8; ++n) {
                        float v = acc[m][n][rr] + bk[n];
                        if (do_relu) v = fmaxf(v, 0.f);
                        if (mode == 1) {
                            __bf16 hb = (__bf16)v;
                            outh[(size_t)row * NODE_D + n * 16 + l15] =
                                __builtin_bit_cast(unsigned short, hb);
                        } else {
                            outf[(size_t)row * NODE_D + n * 16 + l15] = v;
                        }
                    }
                }
            }
        }
    }
}

// ---------------------------------------------------------------------------
// Pool finalize: out[g][j] = gsum[g][j] / max(gs[g+1]-gs[g], 1)
// (bias already folded in during the gemm2 pool epilogue)
// ---------------------------------------------------------------------------
__global__ __launch_bounds__(256) void k_finalize(
    const float* __restrict__ gsum, const int* __restrict__ gs, float* out)
{
    int idx = blockIdx.x * 256 + threadIdx.x;   // 0..8191
    int g = idx >> 7;
    float cnt = (float)(gs[g + 1] - gs[g]);
    out[idx] = gsum[idx] / fmaxf(cnt, 1.0f);
}

// ---------------------------------------------------------------------------
extern "C" void kernel_launch(void* const* d_in, const int* in_sizes, int n_in,
                              void* d_out, int out_size, void* d_ws, size_t ws_size,
                              hipStream_t stream)
{
    const float* x   = (const float*)d_in[0];
    const int*   ei  = (const int*)d_in[1];
    const int*   bat = (const int*)d_in[2];
    const float* W1l = (const float*)d_in[3];
    const float* b1  = (const float*)d_in[4];
    const float* W1r = (const float*)d_in[5];
    const float* W2l = (const float*)d_in[6];
    const float* b2  = (const float*)d_in[7];
    const float* W2r = (const float*)d_in[8];

    const int N = in_sizes[0] / NODE_D;
    const int E = in_sizes[1] / 2;
    const int* srcp = ei;
    const int* dstp = ei + E;
    const int nb = (N + SCHUNK - 1) / SCHUNK;

    // workspace layout (bytes):
    //   [0,       N*256)  xb  bf16
    //   [N*256,  +N*256)  Pb  bf16  (aggregate)
    //   [N*512,  +N*256)  Qb  bf16  (h)
    //   then gsum, gs, deg, offs, cursor(+Wt overlay), partial, srcs
    char* wsb = (char*)d_ws;
    unsigned short* xb = (unsigned short*)wsb;
    unsigned short* Pb = (unsigned short*)(wsb + (size_t)N * 256);
    unsigned short* Qb = (unsigned short*)(wsb + (size_t)N * 512);
    float* gsum = (float*)(wsb + (size_t)N * 768);
    int* gs      = (int*)(gsum + NUM_GRAPHS * NODE_D); // [72] (65 used)
    int* deg     = gs + 72;                           // [N]
    int* offs    = deg + N;                           // [N]
    int* cursor  = offs + N;                          // [N] (dead after k_fill)
    int* partial = cursor + N;                        // [nb]
    int* srcs    = partial + ((nb + 63) & ~63);       // [E]
    // Wt1/Wt2 (64KB each) overlay dead cursor (N ints = 400KB)
    unsigned short* Wt1 = (unsigned short*)cursor;
    unsigned short* Wt2 = Wt1 + 128 * 256;

    hipMemsetAsync(deg, 0, (size_t)N * sizeof(int), stream);
    hipMemsetAsync(gsum, 0, NUM_GRAPHS * NODE_D * sizeof(float), stream);

    // ---- CSR build (once; shared by both layers) + graph bounds
    k_hist<<<(E + 255) / 256, 256, 0, stream>>>(dstp, deg, E);
    k_bounds<<<(N + 255) / 256, 256, 0, stream>>>(bat, gs, N);
    k_scan_partial<<<nb, 256, 0, stream>>>(deg, partial, N);
    k_scan_top<<<1, 64, 0, stream>>>(partial, nb);
    k_scan_final<<<nb, 256, 0, stream>>>(deg, partial, offs, cursor, N);
    k_fill<<<(E + 255) / 256, 256, 0, stream>>>(srcp, dstp, cursor, srcs, E);

    // ---- prep: weights (over dead cursor) + bf16 feature copy
    k_prep2<<<256, 256, 0, stream>>>(W1l, W1r, W2l, W2r, Wt1, Wt2);
    long n8 = (long)N * NODE_D / 8;
    k_prep_x<<<(int)((n8 + 255) / 256), 256, 0, stream>>>(x, xb, n8);

    const int gblk = (N + GROWS - 1) / GROWS;
    // ---- layer 1: mean-agg(xb) -> Pb, then h = relu([Pb||xb]W1) -> Qb (bf16)
    k_gather_bf<<<(N + 7) / 8, 256, 0, stream>>>(xb, srcs, offs, deg, Pb, N);
    k_gemm_mfma<<<gblk, 256, 0, stream>>>(Pb, xb, Wt1, b1, Qb, nullptr, nullptr, N, 1, 1);

    // ---- layer 2: mean-agg(Qb) -> Pb, then pooled gemm: gsum += rows of
    //      [Pb||Qb]W2 + b2, reduced by graph (no per-row y store)
    k_gather_bf<<<(N + 7) / 8, 256, 0, stream>>>(Qb, srcs, offs, deg, Pb, N);
    k_gemm_mfma<<<gblk, 256, 0, stream>>>(Pb, Qb, Wt2, b2, nullptr, bat, gsum, N, 0, 2);

    // ---- finalize: divide by graph size
    k_finalize<<<(NUM_GRAPHS * NODE_D) / 256, 256, 0, stream>>>(gsum, gs, (float*)d_out);
}

// Round 13
// 305.730 us; speedup vs baseline: 1.2725x; 1.2725x over previous
//
#include <hip/hip_runtime.h>

#define NODE_D 128
#define NUM_GRAPHS 64
#define SCHUNK 2048   // elements per scan block (256 thr x 8)

typedef __bf16 v8bf __attribute__((ext_vector_type(8)));
typedef __bf16 v4bf __attribute__((ext_vector_type(4)));
typedef float  v4f  __attribute__((ext_vector_type(4)));

// ---------------------------------------------------------------------------
// CSR step 1 + graph bounds, fused (grid covers max(E,N)):
//   i < E: deg histogram (int atomics)
//   i < N: gs[g] boundaries from sorted batch (handles empty graphs)
// ---------------------------------------------------------------------------
__global__ __launch_bounds__(256) void k_hist_bounds(
    const int* __restrict__ dst, int* deg, int E,
    const int* __restrict__ batch, int* __restrict__ gs, int N)
{
    int i = blockIdx.x * 256 + threadIdx.x;
    if (i < E) atomicAdd(&deg[dst[i]], 1);
    if (i < N) {
        if (i == 0) {
            for (int g = 0; g <= batch[0]; ++g) gs[g] = 0;
        } else {
            int b0 = batch[i - 1], b1 = batch[i];
            for (int g = b0 + 1; g <= b1; ++g) gs[g] = i;
        }
        if (i == N - 1) {
            for (int g = batch[N - 1] + 1; g <= NUM_GRAPHS; ++g) gs[g] = N;
        }
    }
}

// ---------------------------------------------------------------------------
// CSR build, step 2a: per-block partial sums of deg
// ---------------------------------------------------------------------------
__global__ __launch_bounds__(256) void k_scan_partial(
    const int* __restrict__ deg, int* partial, int N)
{
    __shared__ int sbuf[256];
    int base = blockIdx.x * SCHUNK;
    int t = threadIdx.x;
    int s = 0;
#pragma unroll
    for (int i = 0; i < 8; ++i) {
        int idx = base + i * 256 + t;
        if (idx < N) s += deg[idx];
    }
    sbuf[t] = s;
    __syncthreads();
    for (int off = 128; off > 0; off >>= 1) {
        if (t < off) sbuf[t] += sbuf[t + off];
        __syncthreads();
    }
    if (t == 0) partial[blockIdx.x] = sbuf[0];
}

// ---------------------------------------------------------------------------
// CSR build, step 2b: serial exclusive scan of block partials (nb ~ 49)
// ---------------------------------------------------------------------------
__global__ void k_scan_top(int* partial, int nb)
{
    if (threadIdx.x == 0 && blockIdx.x == 0) {
        int run = 0;
        for (int i = 0; i < nb; ++i) { int v = partial[i]; partial[i] = run; run += v; }
    }
}

// ---------------------------------------------------------------------------
// CSR build, step 2c: per-block exclusive scan -> offs, cursor
// ---------------------------------------------------------------------------
__global__ __launch_bounds__(256) void k_scan_final(
    const int* __restrict__ deg, const int* __restrict__ partial,
    int* offs, int* cursor, int N)
{
    __shared__ int sbuf[256];
    int base = blockIdx.x * SCHUNK;
    int t = threadIdx.x;
    int idx0 = base + t * 8;
    int loc[8];
    int s = 0;
#pragma unroll
    for (int i = 0; i < 8; ++i) {
        int idx = idx0 + i;
        int v = (idx < N) ? deg[idx] : 0;
        loc[i] = s;
        s += v;
    }
    sbuf[t] = s;
    __syncthreads();
    for (int off = 1; off < 256; off <<= 1) {
        int tmp = (t >= off) ? sbuf[t - off] : 0;
        __syncthreads();
        sbuf[t] += tmp;
        __syncthreads();
    }
    int pre = sbuf[t] - s + partial[blockIdx.x];
#pragma unroll
    for (int i = 0; i < 8; ++i) {
        int idx = idx0 + i;
        if (idx < N) {
            int v = pre + loc[i];
            offs[idx]   = v;
            cursor[idx] = v;
        }
    }
}

// ---------------------------------------------------------------------------
// CSR build, step 3: bucket src ids into CSR order
// ---------------------------------------------------------------------------
__global__ __launch_bounds__(256) void k_fill(
    const int* __restrict__ src, const int* __restrict__ dst,
    int* cursor, int* srcs, int E)
{
    int e = blockIdx.x * 256 + threadIdx.x;
    if (e < E) {
        int pos = atomicAdd(&cursor[dst[e]], 1);
        srcs[pos] = src[e];
    }
}

// ---------------------------------------------------------------------------
// Prep, fused: idx < n8  -> xb = bf16(x) (8 elems/thread);
//              else      -> weight transpose+convert for both layers.
// ---------------------------------------------------------------------------
__global__ __launch_bounds__(256) void k_prep_all(
    const float* __restrict__ x, unsigned short* __restrict__ xb, long n8,
    const float* __restrict__ W1l, const float* __restrict__ W1r,
    const float* __restrict__ W2l, const float* __restrict__ W2r,
    unsigned short* __restrict__ Wt1, unsigned short* __restrict__ Wt2)
{
    long idx = (long)blockIdx.x * 256 + threadIdx.x;
    if (idx < n8) {
        const float* p = x + idx * 8;
        float4 v0 = *(const float4*)p;
        float4 v1 = *(const float4*)(p + 4);
        v8bf b;
        b[0] = (__bf16)v0.x; b[1] = (__bf16)v0.y; b[2] = (__bf16)v0.z; b[3] = (__bf16)v0.w;
        b[4] = (__bf16)v1.x; b[5] = (__bf16)v1.y; b[6] = (__bf16)v1.z; b[7] = (__bf16)v1.w;
        *(v8bf*)(xb + idx * 8) = b;
        return;
    }
    long w = idx - n8;                 // 0..65535
    if (w >= 65536) return;
    int which = (int)(w >> 15);
    int i = (int)(w & 32767);
    int k = i & 255;
    int c = i >> 8;
    const float* Wl = which ? W2l : W1l;
    const float* Wr = which ? W2r : W1r;
    unsigned short* Wt = which ? Wt2 : Wt1;
    float v = (k < 128) ? Wl[k * 128 + c] : Wr[(k - 128) * 128 + c];
    __bf16 b = (__bf16)v;
    Wt[c * 256 + k] = __builtin_bit_cast(unsigned short, b);
}

// ---------------------------------------------------------------------------
// Pull-aggregate + mean (bf16 in / bf16 out, fp32 accum).
// Half-wave (32 lanes) per node, 8 nodes / 256-thread block.
// Neighbor ids prefetched lane-parallel then broadcast via __shfl.
// ---------------------------------------------------------------------------
__global__ __launch_bounds__(256) void k_gather_bf(
    const unsigned short* __restrict__ Xb, const int* __restrict__ srcs,
    const int* __restrict__ offs, const int* __restrict__ deg,
    unsigned short* __restrict__ outb, int N)
{
    int node = blockIdx.x * 8 + (threadIdx.x >> 5);
    if (node >= N) return;
    int lane  = threadIdx.x & 31;
    int start = offs[node];
    int d     = deg[node];
    float a0 = 0.f, a1 = 0.f, a2 = 0.f, a3 = 0.f;
    for (int base = 0; base < d; base += 32) {
        int cnt = min(d - base, 32);
        int sid = (lane < cnt) ? srcs[start + base + lane] : 0;
        for (int j = 0; j < cnt; ++j) {
            int s = __shfl(sid, j, 32);
            v4bf v = *(const v4bf*)(Xb + (size_t)s * NODE_D + lane * 4);
            a0 += (float)v[0]; a1 += (float)v[1];
            a2 += (float)v[2]; a3 += (float)v[3];
        }
    }
    float r = 1.0f / fmaxf((float)d, 1.0f);
    v4bf o;
    o[0] = (__bf16)(a0 * r); o[1] = (__bf16)(a1 * r);
    o[2] = (__bf16)(a2 * r); o[3] = (__bf16)(a3 * r);
    *(v4bf*)(outb + (size_t)node * NODE_D + lane * 4) = o;
}

// ---------------------------------------------------------------------------
// MFMA SAGE GEMM: y = maybe_relu([A0 || A1] @ W + bias).
// A0, A1 bf16 [N][128]; Wt bf16 [128 cols][256 k] transposed. 4 waves.
// mode 0/1: store y fp32/bf16.
// mode 2: POOL — no y store. Per-thread REGISTER partials ps0/1/2 keyed by
//   rel = batch[row]-batch[row0] (sorted batch -> block spans <=3 graphs;
//   rare rel>=3 falls back to direct global atomics). Lane-group fold via
//   2x shfl_xor; cross-wave via 6KB swsum OVERLAID on dead sA LDS; then
//   384 global atomicAdds/block. (Round-10's 16K LDS atomics/block were a
//   107us serialization disaster -- this replaces them.)
//   mean(z+b): bias added per row; empty graphs stay 0 (matches reference).
// ---------------------------------------------------------------------------
#define GROWS 128
#define GKC   64
#define GSTR  (GKC + 8)   // 72 bf16 rows -> <=2-way bank aliasing (free, m136)
#define PSLOTS 3

__global__ __launch_bounds__(256) void k_gemm_mfma(
    const unsigned short* __restrict__ A0,    // [N][128] bf16 aggregate
    const unsigned short* __restrict__ A1,    // [N][128] bf16 x or h
    const unsigned short* __restrict__ Wt,    // [128][256] bf16 bits
    const float* __restrict__ bias,           // [128] fp32
    void* __restrict__ outp,                  // y out (modes 0/1)
    const int* __restrict__ batch,            // [N] sorted graph ids (mode 2)
    float* __restrict__ gsum_g,               // [64][128] pool accum (mode 2)
    int N, int do_relu, int mode)
{
    __shared__ __bf16 sA[GROWS][GSTR];
    __shared__ __bf16 sW[GROWS][GSTR];

    const int t    = threadIdx.x;
    const int wave = t >> 6;          // 0..3
    const int lane = t & 63;
    const int l15  = lane & 15;
    const int lg   = lane >> 4;       // 0..3
    const int row0 = blockIdx.x * GROWS;

    v4f acc[2][8];
#pragma unroll
    for (int m = 0; m < 2; ++m)
#pragma unroll
        for (int n = 0; n < 8; ++n)
            acc[m][n] = (v4f){0.f, 0.f, 0.f, 0.f};

    float bk[8];
#pragma unroll
    for (int n = 0; n < 8; ++n) bk[n] = bias[n * 16 + l15];

    for (int kc = 0; kc < 4; ++kc) {
        const int kbase = kc * GKC;                       // 0,64,128,192
        const unsigned short* Asrc = (kbase < NODE_D) ? A0 : A1;
        const int koff = kbase & (NODE_D - 1);            // 0 or 64
        // ---- stage A chunk: 128 rows x 64 k bf16. 4 x 16B per thread.
#pragma unroll
        for (int i = 0; i < 4; ++i) {
            int fi = i * 256 + t;     // 0..1023
            int r  = fi >> 3;         // 0..127
            int k8 = fi & 7;          // 0..7
            int row = row0 + r;
            v8bf v = (v8bf)(__bf16)0.f;
            if (row < N) v = *(const v8bf*)(Asrc + (size_t)row * NODE_D + koff + k8 * 8);
            *(v8bf*)&sA[r][k8 * 8] = v;
        }
        // ---- stage W chunk: 128 cols x 64 k bf16. 4 x 16B per thread.
#pragma unroll
        for (int i = 0; i < 4; ++i) {
            int fi = i * 256 + t;     // 0..1023
            int c  = fi >> 3;         // 0..127
            int k8 = fi & 7;          // 0..7
            v8bf w = *(const v8bf*)((const __bf16*)Wt + c * 256 + kbase + k8 * 8);
            *(v8bf*)&sW[c][k8 * 8] = w;
        }
        __syncthreads();
        // ---- compute: 2 k-steps of 32
#pragma unroll
        for (int ks = 0; ks < 2; ++ks) {
            const int kk = ks * 32 + lg * 8;
            v8bf a0 = *(const v8bf*)&sA[wave * 32 +  0 + l15][kk];
            v8bf a1 = *(const v8bf*)&sA[wave * 32 + 16 + l15][kk];
#pragma unroll
            for (int n = 0; n < 8; ++n) {
                v8bf b = *(const v8bf*)&sW[n * 16 + l15][kk];
                acc[0][n] = __builtin_amdgcn_mfma_f32_16x16x32_bf16(a0, b, acc[0][n], 0, 0, 0);
                acc[1][n] = __builtin_amdgcn_mfma_f32_16x16x32_bf16(a1, b, acc[1][n], 0, 0, 0);
            }
        }
        __syncthreads();   // after last iter: all waves done with sA/sW
    }
    // ---- epilogue
    if (mode == 2) {
        const int gfirst = batch[row0 < N ? row0 : (N - 1)];
        float ps0[8], ps1[8], ps2[8];
#pragma unroll
        for (int n = 0; n < 8; ++n) { ps0[n] = 0.f; ps1[n] = 0.f; ps2[n] = 0.f; }
#pragma unroll
        for (int m = 0; m < 2; ++m) {
#pragma unroll
            for (int rr = 0; rr < 4; ++rr) {
                int row = row0 + wave * 32 + m * 16 + lg * 4 + rr;
                if (row < N) {
                    int rel = batch[row] - gfirst;
                    if (rel == 0) {
#pragma unroll
                        for (int n = 0; n < 8; ++n) ps0[n] += acc[m][n][rr] + bk[n];
                    } else if (rel == 1) {
#pragma unroll
                        for (int n = 0; n < 8; ++n) ps1[n] += acc[m][n][rr] + bk[n];
                    } else if (rel == 2) {
#pragma unroll
                        for (int n = 0; n < 8; ++n) ps2[n] += acc[m][n][rr] + bk[n];
                    } else {  // rare: block spans >3 graphs
#pragma unroll
                        for (int n = 0; n < 8; ++n)
                            atomicAdd(&gsum_g[(gfirst + rel) * NODE_D + n * 16 + l15],
                                      acc[m][n][rr] + bk[n]);
                    }
                }
            }
        }
        // fold 4 lane-groups (same col, different rows) via shuffles
#pragma unroll
        for (int n = 0; n < 8; ++n) {
            ps0[n] += __shfl_xor(ps0[n], 16); ps0[n] += __shfl_xor(ps0[n], 32);
            ps1[n] += __shfl_xor(ps1[n], 16); ps1[n] += __shfl_xor(ps1[n], 32);
            ps2[n] += __shfl_xor(ps2[n], 16); ps2[n] += __shfl_xor(ps2[n], 32);
        }
        // cross-wave reduce via LDS overlaid on dead sA (18KB >= 6KB needed)
        float* swsum = (float*)&sA[0][0];   // [4][3][128]
        if (lg == 0) {
#pragma unroll
            for (int n = 0; n < 8; ++n) {
                swsum[(wave * PSLOTS + 0) * NODE_D + n * 16 + l15] = ps0[n];
                swsum[(wave * PSLOTS + 1) * NODE_D + n * 16 + l15] = ps1[n];
                swsum[(wave * PSLOTS + 2) * NODE_D + n * 16 + l15] = ps2[n];
            }
        }
        __syncthreads();
        for (int slot = t; slot < PSLOTS * NODE_D; slot += 256) {
            int rel = slot >> 7;
            int col = slot & 127;
            float v = swsum[(0 * PSLOTS + rel) * NODE_D + col]
                    + swsum[(1 * PSLOTS + rel) * NODE_D + col]
                    + swsum[(2 * PSLOTS + rel) * NODE_D + col]
                    + swsum[(3 * PSLOTS + rel) * NODE_D + col];
            int g = gfirst + rel;
            if (v != 0.f && g < NUM_GRAPHS)
                atomicAdd(&gsum_g[g * NODE_D + col], v);
        }
    } else {
        float* outf = (float*)outp;
        unsigned short* outh = (unsigned short*)outp;
#pragma unroll
        for (int m = 0; m < 2; ++m) {
#pragma unroll
            for (int rr = 0; rr < 4; ++rr) {
                int row = row0 + wave * 32 + m * 16 + lg * 4 + rr;
                if (row < N) {
#pragma unroll
                    for (int n = 0; n < 8; ++n) {
                        float v = acc[m][n][rr] + bk[n];
                        if (do_relu) v = fmaxf(v, 0.f);
                        if (mode == 1) {
                            __bf16 hb = (__bf16)v;
                            outh[(size_t)row * NODE_D + n * 16 + l15] =
                                __builtin_bit_cast(unsigned short, hb);
                        } else {
                            outf[(size_t)row * NODE_D + n * 16 + l15] = v;
                        }
                    }
                }
            }
        }
    }
}

// ---------------------------------------------------------------------------
// Pool finalize: out[g][j] = gsum[g][j] / max(gs[g+1]-gs[g], 1)
// (bias already folded in during the gemm2 pool epilogue)
// ---------------------------------------------------------------------------
__global__ __launch_bounds__(256) void k_finalize(
    const float* __restrict__ gsum, const int* __restrict__ gs, float* out)
{
    int idx = blockIdx.x * 256 + threadIdx.x;   // 0..8191
    int g = idx >> 7;
    float cnt = (float)(gs[g + 1] - gs[g]);
    out[idx] = gsum[idx] / fmaxf(cnt, 1.0f);
}

// ---------------------------------------------------------------------------
extern "C" void kernel_launch(void* const* d_in, const int* in_sizes, int n_in,
                              void* d_out, int out_size, void* d_ws, size_t ws_size,
                              hipStream_t stream)
{
    const float* x   = (const float*)d_in[0];
    const int*   ei  = (const int*)d_in[1];
    const int*   bat = (const int*)d_in[2];
    const float* W1l = (const float*)d_in[3];
    const float* b1  = (const float*)d_in[4];
    const float* W1r = (const float*)d_in[5];
    const float* W2l = (const float*)d_in[6];
    const float* b2  = (const float*)d_in[7];
    const float* W2r = (const float*)d_in[8];

    const int N = in_sizes[0] / NODE_D;
    const int E = in_sizes[1] / 2;
    const int* srcp = ei;
    const int* dstp = ei + E;
    const int nb = (N + SCHUNK - 1) / SCHUNK;

    // workspace layout (bytes):
    //   [0,       N*256)  xb  bf16
    //   [N*256,  +N*256)  Pb  bf16  (aggregate)
    //   [N*512,  +N*256)  Qb  bf16  (h)
    //   gsum [8192 f] + deg [N i]  (ADJACENT -> one memset)
    //   gs[72], offs[N], cursor[N] (+Wt overlay), partial, srcs[E]
    char* wsb = (char*)d_ws;
    unsigned short* xb = (unsigned short*)wsb;
    unsigned short* Pb = (unsigned short*)(wsb + (size_t)N * 256);
    unsigned short* Qb = (unsigned short*)(wsb + (size_t)N * 512);
    float* gsum  = (float*)(wsb + (size_t)N * 768);
    int* deg     = (int*)(gsum + NUM_GRAPHS * NODE_D); // [N]
    int* gs      = deg + N;                            // [72] (65 used)
    int* offs    = gs + 72;                            // [N]
    int* cursor  = offs + N;                           // [N] (dead after k_fill)
    int* partial = cursor + N;                         // [nb]
    int* srcs    = partial + ((nb + 63) & ~63);        // [E]
    // Wt1/Wt2 (64KB each) overlay dead cursor (N ints = 400KB)
    unsigned short* Wt1 = (unsigned short*)cursor;
    unsigned short* Wt2 = Wt1 + 128 * 256;

    // one memset covers gsum + deg (contiguous)
    hipMemsetAsync(gsum, 0, (NUM_GRAPHS * NODE_D + N) * sizeof(int), stream);

    // ---- CSR build + graph bounds (fused)
    const int mx = (E > N ? E : N);
    k_hist_bounds<<<(mx + 255) / 256, 256, 0, stream>>>(dstp, deg, E, bat, gs, N);
    k_scan_partial<<<nb, 256, 0, stream>>>(deg, partial, N);
    k_scan_top<<<1, 64, 0, stream>>>(partial, nb);
    k_scan_final<<<nb, 256, 0, stream>>>(deg, partial, offs, cursor, N);
    k_fill<<<(E + 255) / 256, 256, 0, stream>>>(srcp, dstp, cursor, srcs, E);

    // ---- prep: x->bf16 + both weight transposes (fused; Wt over dead cursor)
    long n8 = (long)N * NODE_D / 8;
    long ptot = n8 + 65536;
    k_prep_all<<<(int)((ptot + 255) / 256), 256, 0, stream>>>(
        x, xb, n8, W1l, W1r, W2l, W2r, Wt1, Wt2);

    const int gblk = (N + GROWS - 1) / GROWS;
    // ---- layer 1: mean-agg(xb) -> Pb, then h = relu([Pb||xb]W1) -> Qb (bf16)
    k_gather_bf<<<(N + 7) / 8, 256, 0, stream>>>(xb, srcs, offs, deg, Pb, N);
    k_gemm_mfma<<<gblk, 256, 0, stream>>>(Pb, xb, Wt1, b1, Qb, nullptr, nullptr, N, 1, 1);

    // ---- layer 2: mean-agg(Qb) -> Pb, then pooled gemm (register-reduced)
    k_gather_bf<<<(N + 7) / 8, 256, 0, stream>>>(Qb, srcs, offs, deg, Pb, N);
    k_gemm_mfma<<<gblk, 256, 0, stream>>>(Pb, Qb, Wt2, b2, nullptr, bat, gsum, N, 0, 2);

    // ---- finalize: divide by graph size
    k_finalize<<<(NUM_GRAPHS * NODE_D) / 256, 256, 0, stream>>>(gsum, gs, (float*)d_out);
}

// Round 14
// 299.056 us; speedup vs baseline: 1.3009x; 1.0223x over previous
//
#include <hip/hip_runtime.h>

#define NODE_D 128
#define NUM_GRAPHS 64
#define SCHUNK 2048   // elements per scan block (256 thr x 8)

typedef __bf16 v8bf __attribute__((ext_vector_type(8)));
typedef __bf16 v4bf __attribute__((ext_vector_type(4)));
typedef float  v4f  __attribute__((ext_vector_type(4)));

// ---------------------------------------------------------------------------
// CSR step 1 + graph bounds, fused (grid covers max(E,N)):
//   i < E: deg histogram (int atomics)
//   i < N: gs[g] boundaries from sorted batch (handles empty graphs)
// ---------------------------------------------------------------------------
__global__ __launch_bounds__(256) void k_hist_bounds(
    const int* __restrict__ dst, int* deg, int E,
    const int* __restrict__ batch, int* __restrict__ gs, int N)
{
    int i = blockIdx.x * 256 + threadIdx.x;
    if (i < E) atomicAdd(&deg[dst[i]], 1);
    if (i < N) {
        if (i == 0) {
            for (int g = 0; g <= batch[0]; ++g) gs[g] = 0;
        } else {
            int b0 = batch[i - 1], b1 = batch[i];
            for (int g = b0 + 1; g <= b1; ++g) gs[g] = i;
        }
        if (i == N - 1) {
            for (int g = batch[N - 1] + 1; g <= NUM_GRAPHS; ++g) gs[g] = N;
        }
    }
}

// ---------------------------------------------------------------------------
// CSR build, step 2a: per-block partial sums of deg
// ---------------------------------------------------------------------------
__global__ __launch_bounds__(256) void k_scan_partial(
    const int* __restrict__ deg, int* partial, int N)
{
    __shared__ int sbuf[256];
    int base = blockIdx.x * SCHUNK;
    int t = threadIdx.x;
    int s = 0;
#pragma unroll
    for (int i = 0; i < 8; ++i) {
        int idx = base + i * 256 + t;
        if (idx < N) s += deg[idx];
    }
    sbuf[t] = s;
    __syncthreads();
    for (int off = 128; off > 0; off >>= 1) {
        if (t < off) sbuf[t] += sbuf[t + off];
        __syncthreads();
    }
    if (t == 0) partial[blockIdx.x] = sbuf[0];
}

// ---------------------------------------------------------------------------
// CSR build, step 2b: serial exclusive scan of block partials (nb ~ 49)
// ---------------------------------------------------------------------------
__global__ void k_scan_top(int* partial, int nb)
{
    if (threadIdx.x == 0 && blockIdx.x == 0) {
        int run = 0;
        for (int i = 0; i < nb; ++i) { int v = partial[i]; partial[i] = run; run += v; }
    }
}

// ---------------------------------------------------------------------------
// CSR build, step 2c: per-block exclusive scan -> offs, cursor
// ---------------------------------------------------------------------------
__global__ __launch_bounds__(256) void k_scan_final(
    const int* __restrict__ deg, const int* __restrict__ partial,
    int* offs, int* cursor, int N)
{
    __shared__ int sbuf[256];
    int base = blockIdx.x * SCHUNK;
    int t = threadIdx.x;
    int idx0 = base + t * 8;
    int loc[8];
    int s = 0;
#pragma unroll
    for (int i = 0; i < 8; ++i) {
        int idx = idx0 + i;
        int v = (idx < N) ? deg[idx] : 0;
        loc[i] = s;
        s += v;
    }
    sbuf[t] = s;
    __syncthreads();
    for (int off = 1; off < 256; off <<= 1) {
        int tmp = (t >= off) ? sbuf[t - off] : 0;
        __syncthreads();
        sbuf[t] += tmp;
        __syncthreads();
    }
    int pre = sbuf[t] - s + partial[blockIdx.x];
#pragma unroll
    for (int i = 0; i < 8; ++i) {
        int idx = idx0 + i;
        if (idx < N) {
            int v = pre + loc[i];
            offs[idx]   = v;
            cursor[idx] = v;
        }
    }
}

// ---------------------------------------------------------------------------
// CSR build, step 3: bucket src ids into CSR order
// ---------------------------------------------------------------------------
__global__ __launch_bounds__(256) void k_fill(
    const int* __restrict__ src, const int* __restrict__ dst,
    int* cursor, int* srcs, int E)
{
    int e = blockIdx.x * 256 + threadIdx.x;
    if (e < E) {
        int pos = atomicAdd(&cursor[dst[e]], 1);
        srcs[pos] = src[e];
    }
}

// ---------------------------------------------------------------------------
// Prep, fused: idx < n8  -> xb = bf16(x) (8 elems/thread);
//              else      -> weight transpose+convert for both layers.
// ---------------------------------------------------------------------------
__global__ __launch_bounds__(256) void k_prep_all(
    const float* __restrict__ x, unsigned short* __restrict__ xb, long n8,
    const float* __restrict__ W1l, const float* __restrict__ W1r,
    const float* __restrict__ W2l, const float* __restrict__ W2r,
    unsigned short* __restrict__ Wt1, unsigned short* __restrict__ Wt2)
{
    long idx = (long)blockIdx.x * 256 + threadIdx.x;
    if (idx < n8) {
        const float* p = x + idx * 8;
        float4 v0 = *(const float4*)p;
        float4 v1 = *(const float4*)(p + 4);
        v8bf b;
        b[0] = (__bf16)v0.x; b[1] = (__bf16)v0.y; b[2] = (__bf16)v0.z; b[3] = (__bf16)v0.w;
        b[4] = (__bf16)v1.x; b[5] = (__bf16)v1.y; b[6] = (__bf16)v1.z; b[7] = (__bf16)v1.w;
        *(v8bf*)(xb + idx * 8) = b;
        return;
    }
    long w = idx - n8;                 // 0..65535
    if (w >= 65536) return;
    int which = (int)(w >> 15);
    int i = (int)(w & 32767);
    int k = i & 255;
    int c = i >> 8;
    const float* Wl = which ? W2l : W1l;
    const float* Wr = which ? W2r : W1r;
    unsigned short* Wt = which ? Wt2 : Wt1;
    float v = (k < 128) ? Wl[k * 128 + c] : Wr[(k - 128) * 128 + c];
    __bf16 b = (__bf16)v;
    Wt[c * 256 + k] = __builtin_bit_cast(unsigned short, b);
}

// ---------------------------------------------------------------------------
// Pull-aggregate + mean (bf16 in / bf16 out, fp32 accum).
// Half-wave (32 lanes) per node, 8 nodes / 256-thread block.
// Neighbor ids prefetched lane-parallel then broadcast via __shfl.
// ---------------------------------------------------------------------------
__global__ __launch_bounds__(256) void k_gather_bf(
    const unsigned short* __restrict__ Xb, const int* __restrict__ srcs,
    const int* __restrict__ offs, const int* __restrict__ deg,
    unsigned short* __restrict__ outb, int N)
{
    int node = blockIdx.x * 8 + (threadIdx.x >> 5);
    if (node >= N) return;
    int lane  = threadIdx.x & 31;
    int start = offs[node];
    int d     = deg[node];
    float a0 = 0.f, a1 = 0.f, a2 = 0.f, a3 = 0.f;
    for (int base = 0; base < d; base += 32) {
        int cnt = min(d - base, 32);
        int sid = (lane < cnt) ? srcs[start + base + lane] : 0;
        for (int j = 0; j < cnt; ++j) {
            int s = __shfl(sid, j, 32);
            v4bf v = *(const v4bf*)(Xb + (size_t)s * NODE_D + lane * 4);
            a0 += (float)v[0]; a1 += (float)v[1];
            a2 += (float)v[2]; a3 += (float)v[3];
        }
    }
    float r = 1.0f / fmaxf((float)d, 1.0f);
    v4bf o;
    o[0] = (__bf16)(a0 * r); o[1] = (__bf16)(a1 * r);
    o[2] = (__bf16)(a2 * r); o[3] = (__bf16)(a3 * r);
    *(v4bf*)(outb + (size_t)node * NODE_D + lane * 4) = o;
}

// ---------------------------------------------------------------------------
// MFMA SAGE GEMM: y = maybe_relu([A0 || A1] @ W + bias).
// A0, A1 bf16 [N][128]; Wt bf16 [128 cols][256 k] transposed.
// BM=64: block = 64 rows x 128 cols, 4 waves, each wave 16 rows (acc[8]).
// (Round-13 profile: BM=128 was latency-bound at 1.3 blocks/CU, MfmaUtil 5%.
//  BM=64 doubles the grid and cuts LDS 36.9->27.6KB for more streams/CU.)
// mode 0/1: store y fp32/bf16.
// mode 2: POOL — register partials + shfl fold + cross-wave LDS overlay,
//   384 global atomics/block. Bias folded per row; empty graphs stay 0.
// ---------------------------------------------------------------------------
#define GROWS 64
#define GKC   64
#define GSTR  (GKC + 8)   // 72 bf16 rows -> <=2-way bank aliasing (free, m136)
#define PSLOTS 3

__global__ __launch_bounds__(256) void k_gemm_mfma(
    const unsigned short* __restrict__ A0,    // [N][128] bf16 aggregate
    const unsigned short* __restrict__ A1,    // [N][128] bf16 x or h
    const unsigned short* __restrict__ Wt,    // [128][256] bf16 bits
    const float* __restrict__ bias,           // [128] fp32
    void* __restrict__ outp,                  // y out (modes 0/1)
    const int* __restrict__ batch,            // [N] sorted graph ids (mode 2)
    float* __restrict__ gsum_g,               // [64][128] pool accum (mode 2)
    int N, int do_relu, int mode)
{
    __shared__ __bf16 sA[GROWS][GSTR];        // 9.2 KB
    __shared__ __bf16 sW[128][GSTR];          // 18.4 KB

    const int t    = threadIdx.x;
    const int wave = t >> 6;          // 0..3 -> rows wave*16..wave*16+15
    const int lane = t & 63;
    const int l15  = lane & 15;
    const int lg   = lane >> 4;       // 0..3
    const int row0 = blockIdx.x * GROWS;

    v4f acc[8];
#pragma unroll
    for (int n = 0; n < 8; ++n) acc[n] = (v4f){0.f, 0.f, 0.f, 0.f};

    float bk[8];
#pragma unroll
    for (int n = 0; n < 8; ++n) bk[n] = bias[n * 16 + l15];

    for (int kc = 0; kc < 4; ++kc) {
        const int kbase = kc * GKC;                       // 0,64,128,192
        const unsigned short* Asrc = (kbase < NODE_D) ? A0 : A1;
        const int koff = kbase & (NODE_D - 1);            // 0 or 64
        // ---- stage A chunk: 64 rows x 64 k bf16 = 512 x 16B, 2 per thread.
#pragma unroll
        for (int i = 0; i < 2; ++i) {
            int fi = i * 256 + t;     // 0..511
            int r  = fi >> 3;         // 0..63
            int k8 = fi & 7;          // 0..7
            int row = row0 + r;
            v8bf v = (v8bf)(__bf16)0.f;
            if (row < N) v = *(const v8bf*)(Asrc + (size_t)row * NODE_D + koff + k8 * 8);
            *(v8bf*)&sA[r][k8 * 8] = v;
        }
        // ---- stage W chunk: 128 cols x 64 k bf16 = 1024 x 16B, 4 per thread.
#pragma unroll
        for (int i = 0; i < 4; ++i) {
            int fi = i * 256 + t;     // 0..1023
            int c  = fi >> 3;         // 0..127
            int k8 = fi & 7;          // 0..7
            v8bf w = *(const v8bf*)((const __bf16*)Wt + c * 256 + kbase + k8 * 8);
            *(v8bf*)&sW[c][k8 * 8] = w;
        }
        __syncthreads();
        // ---- compute: 2 k-steps of 32
#pragma unroll
        for (int ks = 0; ks < 2; ++ks) {
            const int kk = ks * 32 + lg * 8;
            v8bf a = *(const v8bf*)&sA[wave * 16 + l15][kk];
#pragma unroll
            for (int n = 0; n < 8; ++n) {
                v8bf b = *(const v8bf*)&sW[n * 16 + l15][kk];
                acc[n] = __builtin_amdgcn_mfma_f32_16x16x32_bf16(a, b, acc[n], 0, 0, 0);
            }
        }
        __syncthreads();   // after last iter: all waves done with sA/sW
    }
    // ---- epilogue
    if (mode == 2) {
        const int gfirst = batch[row0 < N ? row0 : (N - 1)];
        float ps0[8], ps1[8], ps2[8];
#pragma unroll
        for (int n = 0; n < 8; ++n) { ps0[n] = 0.f; ps1[n] = 0.f; ps2[n] = 0.f; }
#pragma unroll
        for (int rr = 0; rr < 4; ++rr) {
            int row = row0 + wave * 16 + lg * 4 + rr;
            if (row < N) {
                int rel = batch[row] - gfirst;
                if (rel == 0) {
#pragma unroll
                    for (int n = 0; n < 8; ++n) ps0[n] += acc[n][rr] + bk[n];
                } else if (rel == 1) {
#pragma unroll
                    for (int n = 0; n < 8; ++n) ps1[n] += acc[n][rr] + bk[n];
                } else if (rel == 2) {
#pragma unroll
                    for (int n = 0; n < 8; ++n) ps2[n] += acc[n][rr] + bk[n];
                } else {  // rare: block spans >3 graphs
#pragma unroll
                    for (int n = 0; n < 8; ++n)
                        atomicAdd(&gsum_g[(gfirst + rel) * NODE_D + n * 16 + l15],
                                  acc[n][rr] + bk[n]);
                }
            }
        }
        // fold 4 lane-groups (same col, different rows) via shuffles
#pragma unroll
        for (int n = 0; n < 8; ++n) {
            ps0[n] += __shfl_xor(ps0[n], 16); ps0[n] += __shfl_xor(ps0[n], 32);
            ps1[n] += __shfl_xor(ps1[n], 16); ps1[n] += __shfl_xor(ps1[n], 32);
            ps2[n] += __shfl_xor(ps2[n], 16); ps2[n] += __shfl_xor(ps2[n], 32);
        }
        // cross-wave reduce via LDS overlaid on dead sA (9.2KB >= 6KB needed)
        float* swsum = (float*)&sA[0][0];   // [4][3][128]
        if (lg == 0) {
#pragma unroll
            for (int n = 0; n < 8; ++n) {
                swsum[(wave * PSLOTS + 0) * NODE_D + n * 16 + l15] = ps0[n];
                swsum[(wave * PSLOTS + 1) * NODE_D + n * 16 + l15] = ps1[n];
                swsum[(wave * PSLOTS + 2) * NODE_D + n * 16 + l15] = ps2[n];
            }
        }
        __syncthreads();
        for (int slot = t; slot < PSLOTS * NODE_D; slot += 256) {
            int rel = slot >> 7;
            int col = slot & 127;
            float v = swsum[(0 * PSLOTS + rel) * NODE_D + col]
                    + swsum[(1 * PSLOTS + rel) * NODE_D + col]
                    + swsum[(2 * PSLOTS + rel) * NODE_D + col]
                    + swsum[(3 * PSLOTS + rel) * NODE_D + col];
            int g = gfirst + rel;
            if (v != 0.f && g < NUM_GRAPHS)
                atomicAdd(&gsum_g[g * NODE_D + col], v);
        }
    } else {
        float* outf = (float*)outp;
        unsigned short* outh = (unsigned short*)outp;
#pragma unroll
        for (int rr = 0; rr < 4; ++rr) {
            int row = row0 + wave * 16 + lg * 4 + rr;
            if (row < N) {
#pragma unroll
                for (int n = 0; n < 8; ++n) {
                    float v = acc[n][rr] + bk[n];
                    if (do_relu) v = fmaxf(v, 0.f);
                    if (mode == 1) {
                        __bf16 hb = (__bf16)v;
                        outh[(size_t)row * NODE_D + n * 16 + l15] =
                            __builtin_bit_cast(unsigned short, hb);
                    } else {
                        outf[(size_t)row * NODE_D + n * 16 + l15] = v;
                    }
                }
            }
        }
    }
}

// ---------------------------------------------------------------------------
// Pool finalize: out[g][j] = gsum[g][j] / max(gs[g+1]-gs[g], 1)
// (bias already folded in during the gemm2 pool epilogue)
// ---------------------------------------------------------------------------
__global__ __launch_bounds__(256) void k_finalize(
    const float* __restrict__ gsum, const int* __restrict__ gs, float* out)
{
    int idx = blockIdx.x * 256 + threadIdx.x;   // 0..8191
    int g = idx >> 7;
    float cnt = (float)(gs[g + 1] - gs[g]);
    out[idx] = gsum[idx] / fmaxf(cnt, 1.0f);
}

// ---------------------------------------------------------------------------
extern "C" void kernel_launch(void* const* d_in, const int* in_sizes, int n_in,
                              void* d_out, int out_size, void* d_ws, size_t ws_size,
                              hipStream_t stream)
{
    const float* x   = (const float*)d_in[0];
    const int*   ei  = (const int*)d_in[1];
    const int*   bat = (const int*)d_in[2];
    const float* W1l = (const float*)d_in[3];
    const float* b1  = (const float*)d_in[4];
    const float* W1r = (const float*)d_in[5];
    const float* W2l = (const float*)d_in[6];
    const float* b2  = (const float*)d_in[7];
    const float* W2r = (const float*)d_in[8];

    const int N = in_sizes[0] / NODE_D;
    const int E = in_sizes[1] / 2;
    const int* srcp = ei;
    const int* dstp = ei + E;
    const int nb = (N + SCHUNK - 1) / SCHUNK;

    // workspace layout (bytes):
    //   [0,       N*256)  xb  bf16
    //   [N*256,  +N*256)  Pb  bf16  (aggregate)
    //   [N*512,  +N*256)  Qb  bf16  (h)
    //   gsum [8192 f] + deg [N i]  (ADJACENT -> one memset)
    //   gs[72], offs[N], cursor[N] (+Wt overlay), partial, srcs[E]
    char* wsb = (char*)d_ws;
    unsigned short* xb = (unsigned short*)wsb;
    unsigned short* Pb = (unsigned short*)(wsb + (size_t)N * 256);
    unsigned short* Qb = (unsigned short*)(wsb + (size_t)N * 512);
    float* gsum  = (float*)(wsb + (size_t)N * 768);
    int* deg     = (int*)(gsum + NUM_GRAPHS * NODE_D); // [N]
    int* gs      = deg + N;                            // [72] (65 used)
    int* offs    = gs + 72;                            // [N]
    int* cursor  = offs + N;                           // [N] (dead after k_fill)
    int* partial = cursor + N;                         // [nb]
    int* srcs    = partial + ((nb + 63) & ~63);        // [E]
    // Wt1/Wt2 (64KB each) overlay dead cursor (N ints = 400KB)
    unsigned short* Wt1 = (unsigned short*)cursor;
    unsigned short* Wt2 = Wt1 + 128 * 256;

    // one memset covers gsum + deg (contiguous)
    hipMemsetAsync(gsum, 0, (NUM_GRAPHS * NODE_D + N) * sizeof(int), stream);

    // ---- CSR build + graph bounds (fused)
    const int mx = (E > N ? E : N);
    k_hist_bounds<<<(mx + 255) / 256, 256, 0, stream>>>(dstp, deg, E, bat, gs, N);
    k_scan_partial<<<nb, 256, 0, stream>>>(deg, partial, N);
    k_scan_top<<<1, 64, 0, stream>>>(partial, nb);
    k_scan_final<<<nb, 256, 0, stream>>>(deg, partial, offs, cursor, N);
    k_fill<<<(E + 255) / 256, 256, 0, stream>>>(srcp, dstp, cursor, srcs, E);

    // ---- prep: x->bf16 + both weight transposes (fused; Wt over dead cursor)
    long n8 = (long)N * NODE_D / 8;
    long ptot = n8 + 65536;
    k_prep_all<<<(int)((ptot + 255) / 256), 256, 0, stream>>>(
        x, xb, n8, W1l, W1r, W2l, W2r, Wt1, Wt2);

    const int gblk = (N + GROWS - 1) / GROWS;
    // ---- layer 1: mean-agg(xb) -> Pb, then h = relu([Pb||xb]W1) -> Qb (bf16)
    k_gather_bf<<<(N + 7) / 8, 256, 0, stream>>>(xb, srcs, offs, deg, Pb, N);
    k_gemm_mfma<<<gblk, 256, 0, stream>>>(Pb, xb, Wt1, b1, Qb, nullptr, nullptr, N, 1, 1);

    // ---- layer 2: mean-agg(Qb) -> Pb, then pooled gemm (register-reduced)
    k_gather_bf<<<(N + 7) / 8, 256, 0, stream>>>(Qb, srcs, offs, deg, Pb, N);
    k_gemm_mfma<<<gblk, 256, 0, stream>>>(Pb, Qb, Wt2, b2, nullptr, bat, gsum, N, 0, 2);

    // ---- finalize: divide by graph size
    k_finalize<<<(NUM_GRAPHS * NODE_D) / 256, 256, 0, stream>>>(gsum, gs, (float*)d_out);
}